// Round 9
// baseline (118.932 us; speedup 1.0000x reference)
//
#include <hip/hip_runtime.h>

typedef __bf16 bf16x8 __attribute__((ext_vector_type(8)));
typedef __bf16 bf16x4 __attribute__((ext_vector_type(4)));
typedef float  f32x4  __attribute__((ext_vector_type(4)));

#define LOG2E_F 1.44269504088896340736f

static constexpr int kB = 2, kN = 2048, kH = 8, kD = 64, kDim = 512;
static constexpr int kTok = kB * kN;   // 4096
static constexpr int kNQKV = 1536;     // fused Wq(512)+Wkv(1024) rows
static constexpr int kKH = 4;          // attention split-K: 8 kt tiles each

__device__ __forceinline__ void gld16(const void* g, void* l) {
  __builtin_amdgcn_global_load_lds(
      (const __attribute__((address_space(1))) void*)g,
      (__attribute__((address_space(3))) void*)l, 16, 0, 0);
}

// XOR-swizzled LDS tiles (rows of 64 bf16 = 8 chunks of 16B): LDS chunk c of
// row r holds GLOBAL chunk c^(r&7); readers XOR chunk index with (row&7).
// Spreads quad-group b128 reads over all 32 banks.

// ===== fp32 -> bf16 linear converts: x | Wq | Wkv (fused) | Wout ===========
__global__ __launch_bounds__(256) void cvt_all(const float* __restrict__ x,
                                               const float* __restrict__ wq,
                                               const float* __restrict__ wkv,
                                               const float* __restrict__ wo,
                                               __bf16* __restrict__ xb,
                                               __bf16* __restrict__ wqkvb,
                                               __bf16* __restrict__ wob) {
  size_t i = ((size_t)blockIdx.x * 256 + threadIdx.x) * 8;
  const float* s; __bf16* d; size_t off;
  if (i < 2097152)      { s = x;   d = xb;              off = i; }
  else if (i < 2359296) { s = wq;  d = wqkvb;           off = i - 2097152; }
  else if (i < 2883584) { s = wkv; d = wqkvb + 262144;  off = i - 2359296; }
  else                  { s = wo;  d = wob;             off = i - 2883584; }
  float4 u = *(const float4*)(s + off);
  float4 v = *(const float4*)(s + off + 4);
  bf16x8 t;
  t[0] = (__bf16)u.x; t[1] = (__bf16)u.y; t[2] = (__bf16)u.z; t[3] = (__bf16)u.w;
  t[4] = (__bf16)v.x; t[5] = (__bf16)v.y; t[6] = (__bf16)v.z; t[7] = (__bf16)v.w;
  *(bf16x8*)(d + off) = t;
}

// ===== QKV GEMM, 128x128 tile (wave = 64x64), fused norm/transpose =========
__global__ __launch_bounds__(256, 2) void gemm_qkv(const __bf16* __restrict__ A,
                                                   const __bf16* __restrict__ B,
                                                   __bf16* __restrict__ qn,
                                                   __bf16* __restrict__ kn,
                                                   __bf16* __restrict__ vt2) {
  const int K = kDim;
  const int tid = threadIdx.x;
  const int w = tid >> 6, lane = tid & 63, quad = lane >> 4, lq = lane & 15;
  const int m0 = blockIdx.y * 128;
  const int n0 = blockIdx.x * 128;
  const int wm = (w >> 1) * 64, wn = (w & 1) * 64;
  __shared__ __bf16 shm[32768];  // As0|As1|Bs0|Bs1, each 128x64

  const f32x4 zero = {0.f, 0.f, 0.f, 0.f};
  f32x4 acc[4][4];
#pragma unroll
  for (int fm = 0; fm < 4; ++fm)
#pragma unroll
    for (int fn = 0; fn < 4; ++fn) acc[fm][fn] = zero;

  // 128x64 tile = 1024 16B-chunks -> each thread stages 4 chunks per array
  auto stage = [&](int k0, int buf) {
#pragma unroll
    for (int j = 0; j < 4; ++j) {
      const int s = j * 256 + tid;
      const int row = s >> 3, ch = s & 7;
      const int off = k0 + ((ch ^ (row & 7)) << 3);
      gld16(A + (size_t)(m0 + row) * K + off, &shm[buf * 8192 + s * 8]);
      gld16(B + (size_t)(n0 + row) * K + off, &shm[16384 + buf * 8192 + s * 8]);
    }
  };
  const int sw0 = ((quad ^ (lq & 7)) << 3);
  const int sw1 = (((4 | quad) ^ (lq & 7)) << 3);

  stage(0, 0);
  for (int i = 0; i < 8; ++i) {
    __syncthreads();
    if (i < 7) stage((i + 1) << 6, (i + 1) & 1);
    const int ab = (i & 1) * 8192;
#pragma unroll
    for (int ks = 0; ks < 2; ++ks) {
      const int sw = ks ? sw1 : sw0;
      bf16x8 a[4], b[4];
#pragma unroll
      for (int fm = 0; fm < 4; ++fm)
        a[fm] = *(const bf16x8*)&shm[ab + (wm + fm * 16 + lq) * 64 + sw];
#pragma unroll
      for (int fn = 0; fn < 4; ++fn)
        b[fn] = *(const bf16x8*)&shm[16384 + ab + (wn + fn * 16 + lq) * 64 + sw];
#pragma unroll
      for (int fm = 0; fm < 4; ++fm)
#pragma unroll
        for (int fn = 0; fn < 4; ++fn)
          acc[fm][fn] =
              __builtin_amdgcn_mfma_f32_16x16x32_bf16(a[fm], b[fn], acc[fm][fn], 0, 0, 0);
    }
  }

  const int nb = n0 + wn;  // wave's column base (one head's 64 dims)
  if (n0 >= 1024) {
    // ---- V: transpose via LDS (reuse shm: 4 tiles x 64 x 72 = 36 KB) ----
    __syncthreads();
    const int hh = wn >> 6;
    const int b = m0 >> 11, kt0 = (m0 & (kN - 1)) >> 6;
#pragma unroll
    for (int fm = 0; fm < 4; ++fm)
#pragma unroll
      for (int r = 0; r < 4; ++r) {
        const int mo = wm + fm * 16 + quad * 4 + r;  // 0..127
        const int rh = mo >> 6, tt = mo & 63;
        const int p = (tt & 15) * 4 + (tt >> 4);     // inverse of attn's pi
#pragma unroll
        for (int fn = 0; fn < 4; ++fn)
          shm[(hh * 2 + rh) * 4608 + (fn * 16 + lq) * 72 + p] = (__bf16)acc[fm][fn][r];
      }
    __syncthreads();
    const int dd = tid >> 2, p0 = (tid & 3) << 4;
    const int hbase = (n0 >> 6) & 7;
#pragma unroll
    for (int t = 0; t < 4; ++t) {
      const __bf16* src = &shm[t * 4608 + dd * 72 + p0];
      __bf16* dst = vt2 +
          ((size_t)((b * kH + hbase + (t >> 1)) * 32 + kt0 + (t & 1))) * 4096 + tid * 16;
      *(bf16x8*)dst = *(const bf16x8*)src;
      *(bf16x8*)(dst + 8) = *(const bf16x8*)(src + 8);
    }
  } else {
    // ---- Q/K: rms over the wave's 64 cols ----
    const int h = (nb >> 6) & 7;
    const float qs = (nb < 512) ? (0.125f * LOG2E_F) : 1.0f;
    __bf16* dst0 = (nb < 512) ? qn : kn;
#pragma unroll
    for (int fm = 0; fm < 4; ++fm)
#pragma unroll
      for (int r = 0; r < 4; ++r) {
        float ss = 0.f;
#pragma unroll
        for (int fn = 0; fn < 4; ++fn) ss += acc[fm][fn][r] * acc[fm][fn][r];
#pragma unroll
        for (int off = 1; off < 16; off <<= 1) ss += __shfl_xor(ss, off, 64);
        const float inv = qs / (sqrtf(ss * (1.f / 64)) + 1e-4f);
        const int m = m0 + wm + fm * 16 + quad * 4 + r;
        const int b = m >> 11, n = m & (kN - 1);
        __bf16* dst = dst0 + ((size_t)(b * kH + h) * kN + n) * kD;
#pragma unroll
        for (int fn = 0; fn < 4; ++fn)
          dst[fn * 16 + lq] = (__bf16)(acc[fm][fn][r] * inv);
      }
  }
}

// ===== fused attention: 256 q/block, wave = 64 q rows, key-quarter split ===
// Swizzled K/V LDS staging; fixed-max softmax (|s|<=11.54<12, bias -12 in
// MFMA C-init); bf16 partials + fp32 row-sums.
__global__ __launch_bounds__(256, 2) void attn(const __bf16* __restrict__ qn,
                                               const __bf16* __restrict__ kn,
                                               const __bf16* __restrict__ vt2,
                                               __bf16* __restrict__ po,
                                               float* __restrict__ pl) {
  const int qt = blockIdx.x, bh = blockIdx.y, kh = blockIdx.z;
  const int tid = threadIdx.x;
  const int w = tid >> 6, lane = tid & 63, quad = lane >> 4, lq = lane & 15;
  __shared__ __bf16 Ks[2][4096];
  __shared__ __bf16 Vs[2][4096];
  __shared__ __bf16 Ps[4][64 * 72];
  __bf16* myP = &Ps[w][0];

  bf16x8 aq[4][2];
#pragma unroll
  for (int fm = 0; fm < 4; ++fm) {
    const __bf16* Qb = qn + ((size_t)bh * kN + qt * 256 + w * 64 + fm * 16 + lq) * kD;
    aq[fm][0] = *(const bf16x8*)(Qb + quad * 8);
    aq[fm][1] = *(const bf16x8*)(Qb + 32 + quad * 8);
  }

  const f32x4 zero  = {0.f, 0.f, 0.f, 0.f};
  const f32x4 minit = {-12.f, -12.f, -12.f, -12.f};
  f32x4 o[4][4];
  float lr[4][4];
#pragma unroll
  for (int fm = 0; fm < 4; ++fm)
#pragma unroll
    for (int i = 0; i < 4; ++i) { o[fm][i] = zero; lr[fm][i] = 0.f; }

  const __bf16* Kb = kn + (size_t)bh * kN * kD;
  const __bf16* Vb = vt2 + (size_t)bh * 32 * 4096;

  auto stage = [&](int ktg, int buf) {
#pragma unroll
    for (int j = 0; j < 2; ++j) {
      const int s = j * 256 + tid;
      const int row = s >> 3, ch = s & 7;
      const int src = row * 64 + ((ch ^ (row & 7)) << 3);
      gld16(Kb + (size_t)ktg * 4096 + src, &Ks[buf][s * 8]);
      gld16(Vb + (size_t)ktg * 4096 + src, &Vs[buf][s * 8]);
    }
  };
  const int sw0 = ((quad ^ (lq & 7)) << 3);
  const int sw1 = (((4 | quad) ^ (lq & 7)) << 3);

  const int kt0 = kh * 8;
  stage(kt0, 0);
  for (int kt = 0; kt < 8; ++kt) {
    __syncthreads();
    if (kt < 7) stage(kt0 + kt + 1, (kt + 1) & 1);
    const __bf16* ks_ = &Ks[kt & 1][0];
    const __bf16* vs_ = &Vs[kt & 1][0];

    bf16x8 kb0[4], kb1[4];
#pragma unroll
    for (int fn = 0; fn < 4; ++fn) {
      const int rb = (fn * 16 + lq) * 64;
      kb0[fn] = *(const bf16x8*)&ks_[rb + sw0];
      kb1[fn] = *(const bf16x8*)&ks_[rb + sw1];
    }
    // ---- per-fm: S = QK^T - 12, p = exp2(s), P -> wave-private LDS ----
#pragma unroll
    for (int fm = 0; fm < 4; ++fm) {
      f32x4 s[4];
#pragma unroll
      for (int fn = 0; fn < 4; ++fn) {
        f32x4 a = __builtin_amdgcn_mfma_f32_16x16x32_bf16(aq[fm][0], kb0[fn], minit, 0, 0, 0);
        s[fn] = __builtin_amdgcn_mfma_f32_16x16x32_bf16(aq[fm][1], kb1[fn], a, 0, 0, 0);
      }
#pragma unroll
      for (int r = 0; r < 4; ++r) {
        const float p0 = __builtin_amdgcn_exp2f(s[0][r]);
        const float p1 = __builtin_amdgcn_exp2f(s[1][r]);
        const float p2 = __builtin_amdgcn_exp2f(s[2][r]);
        const float p3 = __builtin_amdgcn_exp2f(s[3][r]);
        lr[fm][r] += (p0 + p1) + (p2 + p3);
        bf16x4 pk = {(__bf16)p0, (__bf16)p1, (__bf16)p2, (__bf16)p3};
        *(bf16x4*)&myP[(fm * 16 + quad * 4 + r) * 72 + lq * 4] = pk;
      }
    }
    // ---- O += P V ----
    bf16x8 vb0[4], vb1[4];
#pragma unroll
    for (int fn = 0; fn < 4; ++fn) {
      const int rb = (fn * 16 + lq) * 64;
      vb0[fn] = *(const bf16x8*)&vs_[rb + sw0];
      vb1[fn] = *(const bf16x8*)&vs_[rb + sw1];
    }
#pragma unroll
    for (int fm = 0; fm < 4; ++fm) {
      bf16x8 ap0 = *(const bf16x8*)&myP[(fm * 16 + lq) * 72 + quad * 8];
      bf16x8 ap1 = *(const bf16x8*)&myP[(fm * 16 + lq) * 72 + 32 + quad * 8];
#pragma unroll
      for (int fn = 0; fn < 4; ++fn) {
        o[fm][fn] = __builtin_amdgcn_mfma_f32_16x16x32_bf16(ap0, vb0[fn], o[fm][fn], 0, 0, 0);
        o[fm][fn] = __builtin_amdgcn_mfma_f32_16x16x32_bf16(ap1, vb1[fn], o[fm][fn], 0, 0, 0);
      }
    }
  }

  const int b = bh >> 3, h = bh & 7;
#pragma unroll
  for (int fm = 0; fm < 4; ++fm) {
    const int qrow0 = qt * 256 + w * 64 + fm * 16 + quad * 4;
#pragma unroll
    for (int r = 0; r < 4; ++r) {
      float sum = lr[fm][r];
#pragma unroll
      for (int off = 1; off < 16; off <<= 1) sum += __shfl_xor(sum, off, 64);
      if (lq == 0) pl[(size_t)kh * 32768 + bh * kN + qrow0 + r] = sum;
      const size_t ob = ((size_t)kh * kTok + b * kN + qrow0 + r) * kDim + h * 64;
#pragma unroll
      for (int fn = 0; fn < 4; ++fn) po[ob + fn * 16 + lq] = (__bf16)o[fm][fn][r];
    }
  }
}

// ===== combine quarters: ao = (sum o_kh)/(sum l_kh), bf16 ==================
__global__ __launch_bounds__(256) void combine(const __bf16* __restrict__ po,
                                               const float* __restrict__ pl,
                                               __bf16* __restrict__ ao) {
  const size_t i = ((size_t)blockIdx.x * 256 + threadIdx.x) * 4;
  const int tok = (int)(i >> 9), dk = (int)(i & 511);
  const int h = dk >> 6, b = tok >> 11, qrow = tok & (kN - 1);
  const int idx = (b * kH + h) * kN + qrow;
  float l = 0.f;
#pragma unroll
  for (int kh = 0; kh < kKH; ++kh) l += pl[kh * 32768 + idx];
  const float inv = 1.f / l;
  float s0 = 0.f, s1 = 0.f, s2 = 0.f, s3 = 0.f;
#pragma unroll
  for (int kh = 0; kh < kKH; ++kh) {
    bf16x4 a = *(const bf16x4*)(po + (size_t)kh * kTok * kDim + i);
    s0 += (float)a[0]; s1 += (float)a[1]; s2 += (float)a[2]; s3 += (float)a[3];
  }
  bf16x4 t = {(__bf16)(s0 * inv), (__bf16)(s1 * inv),
              (__bf16)(s2 * inv), (__bf16)(s3 * inv)};
  *(bf16x4*)(ao + i) = t;
}

// ===== out-proj GEMM: C[M,512] = A*B^T, 64x64 tile =========================
__global__ __launch_bounds__(256, 2) void gemm64(const __bf16* __restrict__ A,
                                                 const __bf16* __restrict__ B,
                                                 float* __restrict__ C,
                                                 int N, int K) {
  const int tid = threadIdx.x;
  const int w = tid >> 6, lane = tid & 63, quad = lane >> 4, lq = lane & 15;
  const int m0 = blockIdx.y * 64;
  const int n0 = blockIdx.x * 64;
  const int wm = (w >> 1) * 32, wn = (w & 1) * 32;
  __shared__ __bf16 As[2][4096];
  __shared__ __bf16 Bs[2][4096];

  const f32x4 zero = {0.f, 0.f, 0.f, 0.f};
  f32x4 acc00 = zero, acc01 = zero, acc10 = zero, acc11 = zero;

  const int sr = tid >> 3, ch = tid & 7;
  auto stage = [&](int k0, int buf) {
#pragma unroll
    for (int j = 0; j < 2; ++j) {
      const int row = j * 32 + sr;
      const int src = k0 + ((ch ^ (row & 7)) << 3);
      gld16(A + (size_t)(m0 + row) * K + src, &As[buf][row * 64 + ch * 8]);
      gld16(B + (size_t)(n0 + row) * K + src, &Bs[buf][row * 64 + ch * 8]);
    }
  };
  const int sw0 = ((quad ^ (lq & 7)) << 3);
  const int sw1 = (((4 | quad) ^ (lq & 7)) << 3);

  stage(0, 0);
  const int iters = K >> 6;
  for (int i = 0; i < iters; ++i) {
    __syncthreads();
    if (i + 1 < iters) stage((i + 1) << 6, (i + 1) & 1);
    const __bf16* as = &As[i & 1][0];
    const __bf16* bs = &Bs[i & 1][0];
#pragma unroll
    for (int ks = 0; ks < 2; ++ks) {
      const int sw = ks ? sw1 : sw0;
      bf16x8 a0 = *(const bf16x8*)&as[(wm +      lq) * 64 + sw];
      bf16x8 a1 = *(const bf16x8*)&as[(wm + 16 + lq) * 64 + sw];
      bf16x8 b0 = *(const bf16x8*)&bs[(wn +      lq) * 64 + sw];
      bf16x8 b1 = *(const bf16x8*)&bs[(wn + 16 + lq) * 64 + sw];
      acc00 = __builtin_amdgcn_mfma_f32_16x16x32_bf16(a0, b0, acc00, 0, 0, 0);
      acc01 = __builtin_amdgcn_mfma_f32_16x16x32_bf16(a0, b1, acc01, 0, 0, 0);
      acc10 = __builtin_amdgcn_mfma_f32_16x16x32_bf16(a1, b0, acc10, 0, 0, 0);
      acc11 = __builtin_amdgcn_mfma_f32_16x16x32_bf16(a1, b1, acc11, 0, 0, 0);
    }
  }
  const f32x4 av[2][2] = {{acc00, acc01}, {acc10, acc11}};
#pragma unroll
  for (int fm = 0; fm < 2; ++fm)
#pragma unroll
    for (int fn = 0; fn < 2; ++fn)
#pragma unroll
      for (int r = 0; r < 4; ++r)
        C[(size_t)(m0 + wm + fm * 16 + quad * 4 + r) * N + (n0 + wn + fn * 16 + lq)] =
            av[fm][fn][r];
}

// ===========================================================================
extern "C" void kernel_launch(void* const* d_in, const int* in_sizes, int n_in,
                              void* d_out, int out_size, void* d_ws, size_t ws_size,
                              hipStream_t stream) {
  const float* x    = (const float*)d_in[0];
  const float* Wq   = (const float*)d_in[1];
  const float* Wkv  = (const float*)d_in[2];
  const float* Wout = (const float*)d_in[3];
  float* out = (float*)d_out;
  char* ws = (char*)d_ws;

  __bf16* xb    = (__bf16*)(ws);                       //  0..4M   [4096,512]
  __bf16* wqkvb = (__bf16*)(ws + (size_t)(4 << 20));   //  4..5.5M [1536,512]
  __bf16* wob   = (__bf16*)(ws + (size_t)(6 << 20));   //  6..6.5M [512,512]
  __bf16* qn    = (__bf16*)(ws + (size_t)(7 << 20));   //  7..11M  [bh][n][d]
  __bf16* kn    = (__bf16*)(ws + (size_t)(11 << 20));  // 11..15M  [bh][n][d]
  __bf16* vt2   = (__bf16*)(ws + (size_t)(15 << 20));  // 15..19M  tiled V^T
  __bf16* po    = (__bf16*)(ws + (size_t)(19 << 20));  // 19..35M  partials x4
  float*  pl    = (float*)(ws + (size_t)(35 << 20));   // 35..35.5M
  __bf16* ao    = (__bf16*)(ws + (size_t)(36 << 20));  // 36..40M  [tok][dim]

  cvt_all<<<1536, 256, 0, stream>>>(x, Wq, Wkv, Wout, xb, wqkvb, wob);
  gemm_qkv<<<dim3(kNQKV / 128, kTok / 128), 256, 0, stream>>>(xb, wqkvb, qn, kn, vt2);
  attn<<<dim3(kN / 256, kB * kH, kKH), 256, 0, stream>>>(qn, kn, vt2, po, pl);
  combine<<<kTok * kDim / 1024, 256, 0, stream>>>(po, pl, ao);
  gemm64<<<dim3(kDim / 64, kTok / 64), 256, 0, stream>>>(ao, wob, out, kDim, kDim);
}